// Round 1
// baseline (427.435 us; speedup 1.0000x reference)
//
#include <hip/hip_runtime.h>
#include <hip/hip_bf16.h>
#include <cstdint>
#include <cstddef>

typedef unsigned short u16;
typedef __bf16 bf16x8 __attribute__((ext_vector_type(8)));
typedef float f32x4 __attribute__((ext_vector_type(4)));

#define MFMA_BF16(a, b, c) __builtin_amdgcn_mfma_f32_16x16x32_bf16((a), (b), (c), 0, 0, 0)

// global -> LDS async copy, 16B per lane. LDS layout must be wave-uniform base + lane*16.
#define GLDS16(g, l)                                                        \
  __builtin_amdgcn_global_load_lds(                                         \
      (__attribute__((address_space(1))) void*)(void*)(g),                  \
      (__attribute__((address_space(3))) void*)(void*)(l), 16, 0, 0)

__device__ __forceinline__ u16 f2bf(float x) {
  union { float f; unsigned u; } c; c.f = x;
  unsigned u = c.u;
  unsigned r = (u + 0x7fffu + ((u >> 16) & 1u)) >> 16;  // RNE
  return (u16)r;
}

// ---------------- prologue kernels ----------------

// in: K x N fp32 row-major  ->  out: N x K bf16 row-major (i.e. W^T)
__global__ __launch_bounds__(256) void transpose_bf16_k(
    const float* __restrict__ in, u16* __restrict__ out, int K, int N) {
  __shared__ float tile[32][33];
  const int tx = threadIdx.x & 31, ty = threadIdx.x >> 5;  // 32 x 8
  const int bx = blockIdx.x * 32;  // over N
  const int by = blockIdx.y * 32;  // over K
#pragma unroll
  for (int j = 0; j < 32; j += 8)
    tile[ty + j][tx] = in[(size_t)(by + ty + j) * N + bx + tx];
  __syncthreads();
#pragma unroll
  for (int j = 0; j < 32; j += 8)
    out[(size_t)(bx + ty + j) * K + by + tx] = f2bf(tile[tx][ty + j]);
}

__global__ __launch_bounds__(256) void cvt_bf16_k(
    const float* __restrict__ in, u16* __restrict__ out, int n) {
  int i = (blockIdx.x * 256 + threadIdx.x) * 4;
  if (i + 3 < n) {
    const float4 v = *(const float4*)(in + i);
    ushort4 o;
    o.x = f2bf(v.x); o.y = f2bf(v.y); o.z = f2bf(v.z); o.w = f2bf(v.w);
    *(ushort4*)(out + i) = o;
  }
}

__global__ __launch_bounds__(256) void concat3_k(
    const float* __restrict__ a, const float* __restrict__ b,
    const float* __restrict__ c, float* __restrict__ out) {
  int i = blockIdx.x * 256 + threadIdx.x;
  if (i < 768) out[i] = a[i];
  else if (i < 1536) out[i] = b[i - 768];
  else if (i < 2304) out[i] = c[i - 1536];
}

// ---------------- GEMM: C = A[MxK] @ B^T[NxK]^T + bias ----------------
// 128x128 block tile, 4 waves (2x2), each wave 64x64 = 4x4 mfma 16x16x32 subtiles.
// EPI: 0 = QKV scatter (q,k [B,H,S,64] bf16; v transposed [B,H,64,S] bf16)
//      1 = fp32 out (acc + bias)
//      2 = gelu(acc+bias) -> bf16 out
template <int EPI>
__global__ __launch_bounds__(256) void gemm_bt(
    const u16* __restrict__ A, const u16* __restrict__ BT,
    const float* __restrict__ bias, int M, int N, int K,
    float* __restrict__ outf, u16* __restrict__ outb,
    u16* __restrict__ qo, u16* __restrict__ ko, u16* __restrict__ vto) {
  __shared__ __align__(16) u16 lsA[128 * 32];
  __shared__ __align__(16) u16 lsB[128 * 32];
  const int tid = threadIdx.x;
  const int w = tid >> 6, lane = tid & 63;
  const int wm = w & 1, wn = w >> 1;
  const int lrow = lane & 15, quad = lane >> 4;
  const int m0 = blockIdx.y * 128, n0 = blockIdx.x * 128;

  f32x4 acc[4][4];
#pragma unroll
  for (int i = 0; i < 4; ++i)
#pragma unroll
    for (int j = 0; j < 4; ++j) acc[i][j] = (f32x4){0.f, 0.f, 0.f, 0.f};

  const int off = tid * 16;          // byte offset within 4KB stage chunk
  const int srow = off >> 6;         // 64 B (32 bf16) per row
  const int scol = (off & 63) >> 1;  // element within row

  for (int k0 = 0; k0 < K; k0 += 32) {
    const u16* ga = A + (size_t)(m0 + srow) * K + k0 + scol;
    const u16* gb = BT + (size_t)(n0 + srow) * K + k0 + scol;
    GLDS16(ga, (char*)lsA + off);
    GLDS16(ga + (size_t)64 * K, (char*)lsA + 4096 + off);
    GLDS16(gb, (char*)lsB + off);
    GLDS16(gb + (size_t)64 * K, (char*)lsB + 4096 + off);
    __syncthreads();
    bf16x8 af[4], bfr[4];
#pragma unroll
    for (int ms = 0; ms < 4; ++ms)
      af[ms] = *(const bf16x8*)&lsA[(wm * 64 + ms * 16 + lrow) * 32 + quad * 8];
#pragma unroll
    for (int ns = 0; ns < 4; ++ns)
      bfr[ns] = *(const bf16x8*)&lsB[(wn * 64 + ns * 16 + lrow) * 32 + quad * 8];
#pragma unroll
    for (int ms = 0; ms < 4; ++ms)
#pragma unroll
      for (int ns = 0; ns < 4; ++ns)
        acc[ms][ns] = MFMA_BF16(af[ms], bfr[ns], acc[ms][ns]);
    __syncthreads();
  }

#pragma unroll
  for (int ms = 0; ms < 4; ++ms) {
    const int rbase = m0 + wm * 64 + ms * 16 + quad * 4;
#pragma unroll
    for (int ns = 0; ns < 4; ++ns) {
      const int col = n0 + wn * 64 + ns * 16 + lrow;
      const float bcol = bias[col];
      if constexpr (EPI == 1) {
#pragma unroll
        for (int r = 0; r < 4; ++r)
          outf[(size_t)(rbase + r) * N + col] = acc[ms][ns][r] + bcol;
      } else if constexpr (EPI == 2) {
#pragma unroll
        for (int r = 0; r < 4; ++r) {
          float v = acc[ms][ns][r] + bcol;
          float g = 0.5f * v * (1.0f + erff(v * 0.7071067811865476f));
          outb[(size_t)(rbase + r) * N + col] = f2bf(g);
        }
      } else {  // QKV scatter
        const int which = col / 768;
        const int rem = col - which * 768;
        const int hh = rem >> 6, dd = rem & 63;
        const int bI = rbase >> 11, sI = rbase & 2047;
        const size_t bh = (size_t)bI * 12 + hh;
        if (which == 0) {
#pragma unroll
          for (int r = 0; r < 4; ++r)
            qo[(bh * 2048 + sI + r) * 64 + dd] = f2bf(acc[ms][ns][r] + bcol);
        } else if (which == 1) {
#pragma unroll
          for (int r = 0; r < 4; ++r)
            ko[(bh * 2048 + sI + r) * 64 + dd] = f2bf(acc[ms][ns][r] + bcol);
        } else {
          ushort4 pk;
          pk.x = f2bf(acc[ms][ns][0] + bcol);
          pk.y = f2bf(acc[ms][ns][1] + bcol);
          pk.z = f2bf(acc[ms][ns][2] + bcol);
          pk.w = f2bf(acc[ms][ns][3] + bcol);
          *(ushort4*)(vto + (bh * 64 + dd) * 2048 + sI) = pk;
        }
      }
    }
  }
}

// ---------------- flash attention ----------------
// grid: (S/64, B*H). 4 waves/block, 16 Q rows per wave, K/V tiles of 64.
__global__ __launch_bounds__(256) void attn_kernel(
    const u16* __restrict__ q, const u16* __restrict__ k,
    const u16* __restrict__ vT, u16* __restrict__ ctx) {
  __shared__ __align__(16) u16 lsK[64 * 64];      // [s][d]
  __shared__ __align__(16) u16 lsV[64 * 64];      // [d][s]
  __shared__ __align__(16) u16 lsP[4][16 * 64];   // per-wave [m][j]
  const int tid = threadIdx.x;
  const int w = tid >> 6, lane = tid & 63;
  const int lrow = lane & 15, quad = lane >> 4;
  const int bh = blockIdx.y;
  const int b = bh / 12, h = bh - b * 12;
  const int q0 = blockIdx.x * 64;

  const u16* qbase = q + (size_t)bh * 2048 * 64;
  const u16* kbase = k + (size_t)bh * 2048 * 64;
  const u16* vbase = vT + (size_t)bh * 64 * 2048;

  const int qrow = q0 + w * 16 + lrow;
  const bf16x8 qf0 = *(const bf16x8*)(qbase + (size_t)qrow * 64 + quad * 8);
  const bf16x8 qf1 = *(const bf16x8*)(qbase + (size_t)qrow * 64 + 32 + quad * 8);

  float mst[4], lst[4];
  f32x4 oacc[4];
#pragma unroll
  for (int r = 0; r < 4; ++r) { mst[r] = -1e30f; lst[r] = 0.f; }
#pragma unroll
  for (int d = 0; d < 4; ++d) oacc[d] = (f32x4){0.f, 0.f, 0.f, 0.f};

  const int off = tid * 16;
  const int vd = off >> 7;             // V^T tile row (d), 128B per row
  const int vs = (off & 127) >> 1;     // element in row

  for (int kt = 0; kt < 2048; kt += 64) {
    const u16* ks = kbase + (size_t)kt * 64;  // contiguous 8KB tile
    GLDS16(ks + (off >> 1), (char*)lsK + off);
    GLDS16(ks + 2048 + (off >> 1), (char*)lsK + 4096 + off);
    GLDS16(vbase + (size_t)vd * 2048 + kt + vs, (char*)lsV + off);
    GLDS16(vbase + (size_t)(vd + 32) * 2048 + kt + vs, (char*)lsV + 4096 + off);
    __syncthreads();

    f32x4 sc[4];
#pragma unroll
    for (int ns = 0; ns < 4; ++ns) {
      sc[ns] = (f32x4){0.f, 0.f, 0.f, 0.f};
      bf16x8 kf0 = *(const bf16x8*)&lsK[(ns * 16 + lrow) * 64 + quad * 8];
      bf16x8 kf1 = *(const bf16x8*)&lsK[(ns * 16 + lrow) * 64 + 32 + quad * 8];
      sc[ns] = MFMA_BF16(qf0, kf0, sc[ns]);
      sc[ns] = MFMA_BF16(qf1, kf1, sc[ns]);
      sc[ns] *= 0.125f;  // 1/sqrt(64)
    }

    float alpha[4];
#pragma unroll
    for (int r = 0; r < 4; ++r) {
      float mx = fmaxf(fmaxf(sc[0][r], sc[1][r]), fmaxf(sc[2][r], sc[3][r]));
#pragma unroll
      for (int m = 1; m <= 8; m <<= 1) mx = fmaxf(mx, __shfl_xor(mx, m));
      const float mn = fmaxf(mst[r], mx);
      alpha[r] = __expf(mst[r] - mn);
      float s = 0.f;
#pragma unroll
      for (int ns = 0; ns < 4; ++ns) {
        float p = __expf(sc[ns][r] - mn);
        sc[ns][r] = p;
        s += p;
      }
#pragma unroll
      for (int m = 1; m <= 8; m <<= 1) s += __shfl_xor(s, m);
      lst[r] = lst[r] * alpha[r] + s;
      mst[r] = mn;
    }
#pragma unroll
    for (int d = 0; d < 4; ++d)
#pragma unroll
      for (int r = 0; r < 4; ++r) oacc[d][r] *= alpha[r];

#pragma unroll
    for (int ns = 0; ns < 4; ++ns)
#pragma unroll
      for (int r = 0; r < 4; ++r)
        lsP[w][(quad * 4 + r) * 64 + ns * 16 + lrow] = f2bf(sc[ns][r]);
    __syncthreads();

    const bf16x8 pf0 = *(const bf16x8*)&lsP[w][lrow * 64 + quad * 8];
    const bf16x8 pf1 = *(const bf16x8*)&lsP[w][lrow * 64 + 32 + quad * 8];
#pragma unroll
    for (int d = 0; d < 4; ++d) {
      bf16x8 vf0 = *(const bf16x8*)&lsV[(d * 16 + lrow) * 64 + quad * 8];
      bf16x8 vf1 = *(const bf16x8*)&lsV[(d * 16 + lrow) * 64 + 32 + quad * 8];
      oacc[d] = MFMA_BF16(pf0, vf0, oacc[d]);
      oacc[d] = MFMA_BF16(pf1, vf1, oacc[d]);
    }
    __syncthreads();
  }

  float invl[4];
#pragma unroll
  for (int r = 0; r < 4; ++r) invl[r] = 1.f / lst[r];
  const int srow = q0 + w * 16 + quad * 4;
#pragma unroll
  for (int d = 0; d < 4; ++d)
#pragma unroll
    for (int r = 0; r < 4; ++r)
      ctx[(size_t)(b * 2048 + srow + r) * 768 + h * 64 + d * 16 + lrow] =
          f2bf(oacc[d][r] * invl[r]);
}

// ---------------- residual + layernorm ----------------
__global__ __launch_bounds__(256) void ln_kernel(
    const float* __restrict__ a, const float* __restrict__ res,
    const float* __restrict__ g, const float* __restrict__ bb,
    float* __restrict__ outf, u16* __restrict__ outb) {
  const int row = blockIdx.x;
  const int tid = threadIdx.x;
  const float* pa = a + (size_t)row * 768;
  const float* pr = res + (size_t)row * 768;
  float v[3], s = 0.f, s2 = 0.f;
#pragma unroll
  for (int j = 0; j < 3; ++j) {
    float t = pa[tid + j * 256] + pr[tid + j * 256];
    v[j] = t; s += t; s2 += t * t;
  }
#pragma unroll
  for (int m = 32; m > 0; m >>= 1) {
    s += __shfl_xor(s, m);
    s2 += __shfl_xor(s2, m);
  }
  __shared__ float red[8];
  const int w = tid >> 6, lane = tid & 63;
  if (lane == 0) { red[w] = s; red[4 + w] = s2; }
  __syncthreads();
  s = red[0] + red[1] + red[2] + red[3];
  s2 = red[4] + red[5] + red[6] + red[7];
  const float mu = s * (1.f / 768.f);
  const float var = s2 * (1.f / 768.f) - mu * mu;
  const float rstd = rsqrtf(var + 1e-5f);
#pragma unroll
  for (int j = 0; j < 3; ++j) {
    const int c = tid + j * 256;
    const float y = (v[j] - mu) * rstd * g[c] + bb[c];
    if (outf) outf[(size_t)row * 768 + c] = y;
    if (outb) outb[(size_t)row * 768 + c] = f2bf(y);
  }
}

// ---------------- launch ----------------
extern "C" void kernel_launch(void* const* d_in, const int* in_sizes, int n_in,
                              void* d_out, int out_size, void* d_ws, size_t ws_size,
                              hipStream_t stream) {
  const float* x    = (const float*)d_in[0];
  const float* Wq   = (const float*)d_in[1];
  const float* bq   = (const float*)d_in[2];
  const float* Wk   = (const float*)d_in[3];
  const float* bk   = (const float*)d_in[4];
  const float* Wv   = (const float*)d_in[5];
  const float* bv   = (const float*)d_in[6];
  const float* Wo   = (const float*)d_in[7];
  const float* bo   = (const float*)d_in[8];
  const float* W1   = (const float*)d_in[9];
  const float* b1   = (const float*)d_in[10];
  const float* W2   = (const float*)d_in[11];
  const float* b2   = (const float*)d_in[12];
  const float* ln1g = (const float*)d_in[13];
  const float* ln1b = (const float*)d_in[14];
  const float* ln2g = (const float*)d_in[15];
  const float* ln2b = (const float*)d_in[16];

  char* ws = (char*)d_ws;
  size_t off = 0;
  auto alloc = [&](size_t bytes) {
    void* p = ws + off;
    off += (bytes + 255) & ~(size_t)255;
    return p;
  };
  u16*  WqkvT = (u16*)alloc(2304ull * 768 * 2);
  u16*  WoT   = (u16*)alloc(768ull * 768 * 2);
  u16*  W1T   = (u16*)alloc(3072ull * 768 * 2);
  u16*  W2T   = (u16*)alloc(768ull * 3072 * 2);
  float* bqkv = (float*)alloc(2304 * 4);
  u16*  xb    = (u16*)alloc(4096ull * 768 * 2);
  u16*  qb    = (u16*)alloc(24ull * 2048 * 64 * 2);
  u16*  kb    = (u16*)alloc(24ull * 2048 * 64 * 2);
  u16*  vtb   = (u16*)alloc(24ull * 64 * 2048 * 2);
  u16*  ctx   = (u16*)alloc(4096ull * 768 * 2);
  float* attno = (float*)alloc(4096ull * 768 * 4);
  float* hbuf  = (float*)alloc(4096ull * 768 * 4);
  u16*  hb    = (u16*)alloc(4096ull * 768 * 2);
  u16*  f1    = (u16*)alloc(4096ull * 3072 * 2);
  float* f2b  = (float*)alloc(4096ull * 768 * 4);

  transpose_bf16_k<<<dim3(24, 24), 256, 0, stream>>>(Wq, WqkvT, 768, 768);
  transpose_bf16_k<<<dim3(24, 24), 256, 0, stream>>>(Wk, WqkvT + 768 * 768, 768, 768);
  transpose_bf16_k<<<dim3(24, 24), 256, 0, stream>>>(Wv, WqkvT + 2 * 768 * 768, 768, 768);
  transpose_bf16_k<<<dim3(24, 24), 256, 0, stream>>>(Wo, WoT, 768, 768);
  transpose_bf16_k<<<dim3(96, 24), 256, 0, stream>>>(W1, W1T, 768, 3072);
  transpose_bf16_k<<<dim3(24, 96), 256, 0, stream>>>(W2, W2T, 3072, 768);
  concat3_k<<<9, 256, 0, stream>>>(bq, bk, bv, bqkv);
  cvt_bf16_k<<<3072, 256, 0, stream>>>(x, xb, 4096 * 768);

  gemm_bt<0><<<dim3(18, 32), 256, 0, stream>>>(xb, WqkvT, bqkv, 4096, 2304, 768,
                                               nullptr, nullptr, qb, kb, vtb);
  attn_kernel<<<dim3(32, 24), 256, 0, stream>>>(qb, kb, vtb, ctx);
  gemm_bt<1><<<dim3(6, 32), 256, 0, stream>>>(ctx, WoT, bo, 4096, 768, 768,
                                              attno, nullptr, nullptr, nullptr, nullptr);
  ln_kernel<<<4096, 256, 0, stream>>>(x, attno, ln1g, ln1b, hbuf, hb);
  gemm_bt<2><<<dim3(24, 32), 256, 0, stream>>>(hb, W1T, b1, 4096, 3072, 768,
                                               nullptr, f1, nullptr, nullptr, nullptr);
  gemm_bt<1><<<dim3(6, 32), 256, 0, stream>>>(f1, W2T, b2, 4096, 768, 3072,
                                              f2b, nullptr, nullptr, nullptr, nullptr);
  ln_kernel<<<4096, 256, 0, stream>>>(hbuf, f2b, ln2g, ln2b, (float*)d_out, nullptr);
}

// Round 2
// 357.731 us; speedup vs baseline: 1.1949x; 1.1949x over previous
//
#include <hip/hip_runtime.h>
#include <hip/hip_bf16.h>
#include <cstdint>
#include <cstddef>

typedef unsigned short u16;
typedef __bf16 bf16x8 __attribute__((ext_vector_type(8)));
typedef float f32x4 __attribute__((ext_vector_type(4)));

#define MFMA_BF16(a, b, c) __builtin_amdgcn_mfma_f32_16x16x32_bf16((a), (b), (c), 0, 0, 0)

// global -> LDS async copy, 16B per lane. LDS layout must be wave-uniform base + lane*16.
#define GLDS16(g, l)                                                        \
  __builtin_amdgcn_global_load_lds(                                         \
      (__attribute__((address_space(1))) void*)(void*)(g),                  \
      (__attribute__((address_space(3))) void*)(void*)(l), 16, 0, 0)

// scale folded into q at QKV epilogue: 1/sqrt(64) * log2(e), so softmax uses exp2 directly
#define QSCALE 0.18033688011112042f

__device__ __forceinline__ u16 f2bf(float x) {
  union { float f; unsigned u; } c; c.f = x;
  unsigned u = c.u;
  unsigned r = (u + 0x7fffu + ((u >> 16) & 1u)) >> 16;  // RNE
  return (u16)r;
}

// ---------------- prologue kernels ----------------

// in: K x N fp32 row-major  ->  out: N x K bf16 row-major (i.e. W^T)
__global__ __launch_bounds__(256) void transpose_bf16_k(
    const float* __restrict__ in, u16* __restrict__ out, int K, int N) {
  __shared__ float tile[32][33];
  const int tx = threadIdx.x & 31, ty = threadIdx.x >> 5;  // 32 x 8
  const int bx = blockIdx.x * 32;  // over N
  const int by = blockIdx.y * 32;  // over K
#pragma unroll
  for (int j = 0; j < 32; j += 8)
    tile[ty + j][tx] = in[(size_t)(by + ty + j) * N + bx + tx];
  __syncthreads();
#pragma unroll
  for (int j = 0; j < 32; j += 8)
    out[(size_t)(bx + ty + j) * K + by + tx] = f2bf(tile[tx][ty + j]);
}

__global__ __launch_bounds__(256) void cvt_bf16_k(
    const float* __restrict__ in, u16* __restrict__ out, int n) {
  int i = (blockIdx.x * 256 + threadIdx.x) * 4;
  if (i + 3 < n) {
    const float4 v = *(const float4*)(in + i);
    ushort4 o;
    o.x = f2bf(v.x); o.y = f2bf(v.y); o.z = f2bf(v.z); o.w = f2bf(v.w);
    *(ushort4*)(out + i) = o;
  }
}

__global__ __launch_bounds__(256) void concat3_k(
    const float* __restrict__ a, const float* __restrict__ b,
    const float* __restrict__ c, float* __restrict__ out) {
  int i = blockIdx.x * 256 + threadIdx.x;
  if (i < 768) out[i] = a[i];
  else if (i < 1536) out[i] = b[i - 768];
  else if (i < 2304) out[i] = c[i - 1536];
}

// ---------------- GEMM: C = A[MxK] @ B^T[NxK]^T + bias ----------------
// 128x128 block tile, 4 waves (2x2), each wave 64x64 = 4x4 mfma 16x16x32 subtiles.
// EPI: 0 = QKV scatter (q scaled by QSCALE; q,k [B,H,S,64] bf16; v transposed [B,H,64,S])
//      1 = fp32 out (acc + bias)
//      2 = gelu(acc+bias) -> bf16 out
template <int EPI>
__global__ __launch_bounds__(256) void gemm_bt(
    const u16* __restrict__ A, const u16* __restrict__ BT,
    const float* __restrict__ bias, int M, int N, int K,
    float* __restrict__ outf, u16* __restrict__ outb,
    u16* __restrict__ qo, u16* __restrict__ ko, u16* __restrict__ vto) {
  __shared__ __align__(16) u16 lsA[128 * 32];
  __shared__ __align__(16) u16 lsB[128 * 32];
  const int tid = threadIdx.x;
  const int w = tid >> 6, lane = tid & 63;
  const int wm = w & 1, wn = w >> 1;
  const int lrow = lane & 15, quad = lane >> 4;
  const int m0 = blockIdx.y * 128, n0 = blockIdx.x * 128;

  f32x4 acc[4][4];
#pragma unroll
  for (int i = 0; i < 4; ++i)
#pragma unroll
    for (int j = 0; j < 4; ++j) acc[i][j] = (f32x4){0.f, 0.f, 0.f, 0.f};

  const int off = tid * 16;          // byte offset within 4KB stage chunk
  const int srow = off >> 6;         // 64 B (32 bf16) per row
  const int scol = (off & 63) >> 1;  // element within row

  for (int k0 = 0; k0 < K; k0 += 32) {
    const u16* ga = A + (size_t)(m0 + srow) * K + k0 + scol;
    const u16* gb = BT + (size_t)(n0 + srow) * K + k0 + scol;
    GLDS16(ga, (char*)lsA + off);
    GLDS16(ga + (size_t)64 * K, (char*)lsA + 4096 + off);
    GLDS16(gb, (char*)lsB + off);
    GLDS16(gb + (size_t)64 * K, (char*)lsB + 4096 + off);
    __syncthreads();
    bf16x8 af[4], bfr[4];
#pragma unroll
    for (int ms = 0; ms < 4; ++ms)
      af[ms] = *(const bf16x8*)&lsA[(wm * 64 + ms * 16 + lrow) * 32 + quad * 8];
#pragma unroll
    for (int ns = 0; ns < 4; ++ns)
      bfr[ns] = *(const bf16x8*)&lsB[(wn * 64 + ns * 16 + lrow) * 32 + quad * 8];
#pragma unroll
    for (int ms = 0; ms < 4; ++ms)
#pragma unroll
      for (int ns = 0; ns < 4; ++ns)
        acc[ms][ns] = MFMA_BF16(af[ms], bfr[ns], acc[ms][ns]);
    __syncthreads();
  }

#pragma unroll
  for (int ms = 0; ms < 4; ++ms) {
    const int rbase = m0 + wm * 64 + ms * 16 + quad * 4;
#pragma unroll
    for (int ns = 0; ns < 4; ++ns) {
      const int col = n0 + wn * 64 + ns * 16 + lrow;
      const float bcol = bias[col];
      if constexpr (EPI == 1) {
#pragma unroll
        for (int r = 0; r < 4; ++r)
          outf[(size_t)(rbase + r) * N + col] = acc[ms][ns][r] + bcol;
      } else if constexpr (EPI == 2) {
#pragma unroll
        for (int r = 0; r < 4; ++r) {
          float v = acc[ms][ns][r] + bcol;
          float g = 0.5f * v * (1.0f + erff(v * 0.7071067811865476f));
          outb[(size_t)(rbase + r) * N + col] = f2bf(g);
        }
      } else {  // QKV scatter
        const int which = col / 768;
        const int rem = col - which * 768;
        const int hh = rem >> 6, dd = rem & 63;
        const int bI = rbase >> 11, sI = rbase & 2047;
        const size_t bh = (size_t)bI * 12 + hh;
        if (which == 0) {
#pragma unroll
          for (int r = 0; r < 4; ++r)
            qo[(bh * 2048 + sI + r) * 64 + dd] = f2bf((acc[ms][ns][r] + bcol) * QSCALE);
        } else if (which == 1) {
#pragma unroll
          for (int r = 0; r < 4; ++r)
            ko[(bh * 2048 + sI + r) * 64 + dd] = f2bf(acc[ms][ns][r] + bcol);
        } else {
          ushort4 pk;
          pk.x = f2bf(acc[ms][ns][0] + bcol);
          pk.y = f2bf(acc[ms][ns][1] + bcol);
          pk.z = f2bf(acc[ms][ns][2] + bcol);
          pk.w = f2bf(acc[ms][ns][3] + bcol);
          *(ushort4*)(vto + (bh * 64 + dd) * 2048 + sI) = pk;
        }
      }
    }
  }
}

// ---------------- flash attention (softmax-lite, XOR-swizzled LDS) ----------------
// grid: (S/64, B*H). 4 waves/block, 16 Q rows per wave, K/V tiles of 64.
// No online max: q pre-scaled by 1/8*log2(e), P = exp2(S2); denominators reduced once at end.
// LDS rows are 128B = 8 chunks of 16B; chunk c of row r lives at slot c^(r&7).
__global__ __launch_bounds__(256) void attn_kernel(
    const u16* __restrict__ q, const u16* __restrict__ k,
    const u16* __restrict__ vT, u16* __restrict__ ctx) {
  __shared__ __align__(16) u16 lsK[64 * 64];      // [s][d], swizzled
  __shared__ __align__(16) u16 lsV[64 * 64];      // [d][s], swizzled
  __shared__ __align__(16) u16 lsP[4][16 * 64];   // per-wave [m][j], swizzled
  const int tid = threadIdx.x;
  const int w = tid >> 6, lane = tid & 63;
  const int lrow = lane & 15, quad = lane >> 4;
  const int bh = blockIdx.y;
  const int b = bh / 12, h = bh - b * 12;
  const int q0 = blockIdx.x * 64;

  const u16* qbase = q + (size_t)bh * 2048 * 64;
  const u16* kbase = k + (size_t)bh * 2048 * 64;
  const u16* vbase = vT + (size_t)bh * 64 * 2048;

  const int qrow = q0 + w * 16 + lrow;
  const bf16x8 qf0 = *(const bf16x8*)(qbase + (size_t)qrow * 64 + quad * 8);
  const bf16x8 qf1 = *(const bf16x8*)(qbase + (size_t)qrow * 64 + 32 + quad * 8);

  float lsum[4] = {0.f, 0.f, 0.f, 0.f};
  f32x4 oacc[4];
#pragma unroll
  for (int d = 0; d < 4; ++d) oacc[d] = (f32x4){0.f, 0.f, 0.f, 0.f};

  // staging mapping: lane covers byte `off` of a 4KB half-tile; source chunk is swizzled
  const int off = tid * 16;
  const int srow = off >> 7;               // 0..31 (row within half-tile)
  const int schunk = (off >> 4) & 7;       // chunk slot within row
  const int sxc = schunk ^ (srow & 7);     // source chunk
  const int ksrc = srow * 64 + sxc * 8;    // u16 offset within K half-tile
  const int vsrc0 = srow * 2048 + sxc * 8; // u16 offset for V (row d=srow)

  // fragment read chunk: logical chunk quad (and quad^4), row parity = lrow&7
  const int c0 = quad ^ (lrow & 7);
  const int rd0 = c0 * 8, rd1 = (c0 ^ 4) * 8;  // u16 offsets within a row

  u16* const lsPw = &lsP[w][0];
  const int jhi_base = lrow >> 3, jlo = lrow & 7;

  for (int kt = 0; kt < 2048; kt += 64) {
    GLDS16(kbase + (size_t)kt * 64 + ksrc, (char*)lsK + off);
    GLDS16(kbase + (size_t)(kt + 32) * 64 + ksrc, (char*)lsK + 4096 + off);
    GLDS16(vbase + vsrc0 + kt, (char*)lsV + off);
    GLDS16(vbase + vsrc0 + kt + 32 * 2048, (char*)lsV + 4096 + off);
    __syncthreads();

    f32x4 sc[4];
#pragma unroll
    for (int ns = 0; ns < 4; ++ns) {
      sc[ns] = (f32x4){0.f, 0.f, 0.f, 0.f};
      const u16* kr = &lsK[(ns * 16 + lrow) * 64];
      bf16x8 kf0 = *(const bf16x8*)(kr + rd0);
      bf16x8 kf1 = *(const bf16x8*)(kr + rd1);
      sc[ns] = MFMA_BF16(qf0, kf0, sc[ns]);
      sc[ns] = MFMA_BF16(qf1, kf1, sc[ns]);
    }

    // P = exp2(S); accumulate denom per lane; store P (trunc to bf16) to swizzled lsP
#pragma unroll
    for (int ns = 0; ns < 4; ++ns) {
      const int jhi = ns * 2 + jhi_base;
#pragma unroll
      for (int r = 0; r < 4; ++r) {
        float p = __builtin_amdgcn_exp2f(sc[ns][r]);
        lsum[r] += p;
        union { float f; unsigned u; } cv; cv.f = p;
        const int m = quad * 4 + r;
        lsPw[m * 64 + ((jhi ^ (m & 7)) * 8) + jlo] = (u16)(cv.u >> 16);
      }
    }

    // PV (wave-private P: same-wave DS ordering, no barrier needed)
    const u16* pr = lsPw + lrow * 64;
    const bf16x8 pf0 = *(const bf16x8*)(pr + rd0);
    const bf16x8 pf1 = *(const bf16x8*)(pr + rd1);
#pragma unroll
    for (int d = 0; d < 4; ++d) {
      const u16* vr = &lsV[(d * 16 + lrow) * 64];
      bf16x8 vf0 = *(const bf16x8*)(vr + rd0);
      bf16x8 vf1 = *(const bf16x8*)(vr + rd1);
      oacc[d] = MFMA_BF16(pf0, vf0, oacc[d]);
      oacc[d] = MFMA_BF16(pf1, vf1, oacc[d]);
    }
    __syncthreads();
  }

  // reduce denominators across lrow lanes (lane bits 0-3), once
#pragma unroll
  for (int r = 0; r < 4; ++r) {
#pragma unroll
    for (int mm = 1; mm <= 8; mm <<= 1) lsum[r] += __shfl_xor(lsum[r], mm);
  }
  float invl[4];
#pragma unroll
  for (int r = 0; r < 4; ++r) invl[r] = 1.f / lsum[r];

  const int srow_out = q0 + w * 16 + quad * 4;
#pragma unroll
  for (int d = 0; d < 4; ++d)
#pragma unroll
    for (int r = 0; r < 4; ++r)
      ctx[(size_t)(b * 2048 + srow_out + r) * 768 + h * 64 + d * 16 + lrow] =
          f2bf(oacc[d][r] * invl[r]);
}

// ---------------- residual + layernorm ----------------
__global__ __launch_bounds__(256) void ln_kernel(
    const float* __restrict__ a, const float* __restrict__ res,
    const float* __restrict__ g, const float* __restrict__ bb,
    float* __restrict__ outf, u16* __restrict__ outb) {
  const int row = blockIdx.x;
  const int tid = threadIdx.x;
  const float* pa = a + (size_t)row * 768;
  const float* pr = res + (size_t)row * 768;
  float v[3], s = 0.f, s2 = 0.f;
#pragma unroll
  for (int j = 0; j < 3; ++j) {
    float t = pa[tid + j * 256] + pr[tid + j * 256];
    v[j] = t; s += t; s2 += t * t;
  }
#pragma unroll
  for (int m = 32; m > 0; m >>= 1) {
    s += __shfl_xor(s, m);
    s2 += __shfl_xor(s2, m);
  }
  __shared__ float red[8];
  const int w = tid >> 6, lane = tid & 63;
  if (lane == 0) { red[w] = s; red[4 + w] = s2; }
  __syncthreads();
  s = red[0] + red[1] + red[2] + red[3];
  s2 = red[4] + red[5] + red[6] + red[7];
  const float mu = s * (1.f / 768.f);
  const float var = s2 * (1.f / 768.f) - mu * mu;
  const float rstd = rsqrtf(var + 1e-5f);
#pragma unroll
  for (int j = 0; j < 3; ++j) {
    const int c = tid + j * 256;
    const float y = (v[j] - mu) * rstd * g[c] + bb[c];
    if (outf) outf[(size_t)row * 768 + c] = y;
    if (outb) outb[(size_t)row * 768 + c] = f2bf(y);
  }
}

// ---------------- launch ----------------
extern "C" void kernel_launch(void* const* d_in, const int* in_sizes, int n_in,
                              void* d_out, int out_size, void* d_ws, size_t ws_size,
                              hipStream_t stream) {
  const float* x    = (const float*)d_in[0];
  const float* Wq   = (const float*)d_in[1];
  const float* bq   = (const float*)d_in[2];
  const float* Wk   = (const float*)d_in[3];
  const float* bk   = (const float*)d_in[4];
  const float* Wv   = (const float*)d_in[5];
  const float* bv   = (const float*)d_in[6];
  const float* Wo   = (const float*)d_in[7];
  const float* bo   = (const float*)d_in[8];
  const float* W1   = (const float*)d_in[9];
  const float* b1   = (const float*)d_in[10];
  const float* W2   = (const float*)d_in[11];
  const float* b2   = (const float*)d_in[12];
  const float* ln1g = (const float*)d_in[13];
  const float* ln1b = (const float*)d_in[14];
  const float* ln2g = (const float*)d_in[15];
  const float* ln2b = (const float*)d_in[16];

  char* ws = (char*)d_ws;
  size_t off = 0;
  auto alloc = [&](size_t bytes) {
    void* p = ws + off;
    off += (bytes + 255) & ~(size_t)255;
    return p;
  };
  u16*  WqkvT = (u16*)alloc(2304ull * 768 * 2);
  u16*  WoT   = (u16*)alloc(768ull * 768 * 2);
  u16*  W1T   = (u16*)alloc(3072ull * 768 * 2);
  u16*  W2T   = (u16*)alloc(768ull * 3072 * 2);
  float* bqkv = (float*)alloc(2304 * 4);
  u16*  xb    = (u16*)alloc(4096ull * 768 * 2);
  u16*  qb    = (u16*)alloc(24ull * 2048 * 64 * 2);
  u16*  kb    = (u16*)alloc(24ull * 2048 * 64 * 2);
  u16*  vtb   = (u16*)alloc(24ull * 64 * 2048 * 2);
  u16*  ctx   = (u16*)alloc(4096ull * 768 * 2);
  float* attno = (float*)alloc(4096ull * 768 * 4);
  float* hbuf  = (float*)alloc(4096ull * 768 * 4);
  u16*  hb    = (u16*)alloc(4096ull * 768 * 2);
  u16*  f1    = (u16*)alloc(4096ull * 3072 * 2);
  float* f2b  = (float*)alloc(4096ull * 768 * 4);

  transpose_bf16_k<<<dim3(24, 24), 256, 0, stream>>>(Wq, WqkvT, 768, 768);
  transpose_bf16_k<<<dim3(24, 24), 256, 0, stream>>>(Wk, WqkvT + 768 * 768, 768, 768);
  transpose_bf16_k<<<dim3(24, 24), 256, 0, stream>>>(Wv, WqkvT + 2 * 768 * 768, 768, 768);
  transpose_bf16_k<<<dim3(24, 24), 256, 0, stream>>>(Wo, WoT, 768, 768);
  transpose_bf16_k<<<dim3(96, 24), 256, 0, stream>>>(W1, W1T, 768, 3072);
  transpose_bf16_k<<<dim3(24, 96), 256, 0, stream>>>(W2, W2T, 3072, 768);
  concat3_k<<<9, 256, 0, stream>>>(bq, bk, bv, bqkv);
  cvt_bf16_k<<<3072, 256, 0, stream>>>(x, xb, 4096 * 768);

  gemm_bt<0><<<dim3(18, 32), 256, 0, stream>>>(xb, WqkvT, bqkv, 4096, 2304, 768,
                                               nullptr, nullptr, qb, kb, vtb);
  attn_kernel<<<dim3(32, 24), 256, 0, stream>>>(qb, kb, vtb, ctx);
  gemm_bt<1><<<dim3(6, 32), 256, 0, stream>>>(ctx, WoT, bo, 4096, 768, 768,
                                              attno, nullptr, nullptr, nullptr, nullptr);
  ln_kernel<<<4096, 256, 0, stream>>>(x, attno, ln1g, ln1b, hbuf, hb);
  gemm_bt<2><<<dim3(24, 32), 256, 0, stream>>>(hb, W1T, b1, 4096, 3072, 768,
                                               nullptr, f1, nullptr, nullptr, nullptr);
  gemm_bt<1><<<dim3(6, 32), 256, 0, stream>>>(f1, W2T, b2, 4096, 768, 3072,
                                              f2b, nullptr, nullptr, nullptr, nullptr);
  ln_kernel<<<4096, 256, 0, stream>>>(hbuf, f2b, ln2g, ln2b, (float*)d_out, nullptr);
}

// Round 3
// 312.243 us; speedup vs baseline: 1.3689x; 1.1457x over previous
//
#include <hip/hip_runtime.h>
#include <hip/hip_bf16.h>
#include <cstdint>
#include <cstddef>

typedef unsigned short u16;
typedef __bf16 bf16x8 __attribute__((ext_vector_type(8)));
typedef float f32x4 __attribute__((ext_vector_type(4)));

#define MFMA_BF16(a, b, c) __builtin_amdgcn_mfma_f32_16x16x32_bf16((a), (b), (c), 0, 0, 0)

// global -> LDS async copy, 16B per lane. LDS layout must be wave-uniform base + lane*16.
#define GLDS16(g, l)                                                        \
  __builtin_amdgcn_global_load_lds(                                         \
      (__attribute__((address_space(1))) void*)(void*)(g),                  \
      (__attribute__((address_space(3))) void*)(void*)(l), 16, 0, 0)

// scale folded into q at QKV epilogue: 1/sqrt(64) * log2(e), so softmax uses exp2 directly
#define QSCALE 0.18033688011112042f
#define PSTRIDE ((size_t)4096 * 768)

__device__ __forceinline__ u16 f2bf(float x) {
  union { float f; unsigned u; } c; c.f = x;
  unsigned u = c.u;
  unsigned r = (u + 0x7fffu + ((u >> 16) & 1u)) >> 16;  // RNE
  return (u16)r;
}

// ---------------- prologue kernels ----------------

// in: K x N fp32 row-major  ->  out: N x K bf16 row-major (i.e. W^T)
__global__ __launch_bounds__(256) void transpose_bf16_k(
    const float* __restrict__ in, u16* __restrict__ out, int K, int N) {
  __shared__ float tile[32][33];
  const int tx = threadIdx.x & 31, ty = threadIdx.x >> 5;  // 32 x 8
  const int bx = blockIdx.x * 32;  // over N
  const int by = blockIdx.y * 32;  // over K
#pragma unroll
  for (int j = 0; j < 32; j += 8)
    tile[ty + j][tx] = in[(size_t)(by + ty + j) * N + bx + tx];
  __syncthreads();
#pragma unroll
  for (int j = 0; j < 32; j += 8)
    out[(size_t)(bx + ty + j) * K + by + tx] = f2bf(tile[tx][ty + j]);
}

__global__ __launch_bounds__(256) void cvt_bf16_k(
    const float* __restrict__ in, u16* __restrict__ out, int n) {
  int i = (blockIdx.x * 256 + threadIdx.x) * 4;
  if (i + 3 < n) {
    const float4 v = *(const float4*)(in + i);
    ushort4 o;
    o.x = f2bf(v.x); o.y = f2bf(v.y); o.z = f2bf(v.z); o.w = f2bf(v.w);
    *(ushort4*)(out + i) = o;
  }
}

__global__ __launch_bounds__(256) void concat3_k(
    const float* __restrict__ a, const float* __restrict__ b,
    const float* __restrict__ c, float* __restrict__ out) {
  int i = blockIdx.x * 256 + threadIdx.x;
  if (i < 768) out[i] = a[i];
  else if (i < 1536) out[i] = b[i - 768];
  else if (i < 2304) out[i] = c[i - 1536];
}

// ---------------- GEMM: C = A[MxK] @ B^T[NxK]^T (+ bias) ----------------
// 128x128 block tile, 4 waves (2x2), each wave 64x64 = 4x4 mfma 16x16x32 subtiles.
// BK=64 (32 MFMAs/wave between barriers). LDS rows 128B = 8 chunks of 16B,
// chunk c of row r stored at slot c^(r&7) (conflict-free reads, staging stays
// wave-uniform-base + lane*16).
// Split-K via gridDim.z: chunk kchunk = K/gridDim.z, EPI=3 writes fp32 partials.
// EPI: 0 = QKV scatter (q scaled by QSCALE; q,k [B,H,S,64] bf16; v transposed [B,H,64,S])
//      2 = gelu(acc+bias) -> bf16 out
//      3 = fp32 partial (no bias) at outf + blockIdx.z*M*N
template <int EPI>
__global__ __launch_bounds__(256) void gemm_bt(
    const u16* __restrict__ A, const u16* __restrict__ BT,
    const float* __restrict__ bias, int M, int N, int K, int kchunk,
    float* __restrict__ outf, u16* __restrict__ outb,
    u16* __restrict__ qo, u16* __restrict__ ko, u16* __restrict__ vto) {
  __shared__ __align__(16) u16 lsA[128 * 64];
  __shared__ __align__(16) u16 lsB[128 * 64];
  const int tid = threadIdx.x;
  const int w = tid >> 6, lane = tid & 63;
  const int wm = w & 1, wn = w >> 1;
  const int lrow = lane & 15, quad = lane >> 4;
  const int m0 = blockIdx.y * 128, n0 = blockIdx.x * 128;
  const int kbeg = blockIdx.z * kchunk, kend = kbeg + kchunk;

  f32x4 acc[4][4];
#pragma unroll
  for (int i = 0; i < 4; ++i)
#pragma unroll
    for (int j = 0; j < 4; ++j) acc[i][j] = (f32x4){0.f, 0.f, 0.f, 0.f};

  // staging: 256 threads cover one 4KB chunk (32 rows x 128B); 4 chunks per matrix
  const int off = tid * 16;                 // byte offset within 4KB chunk
  const int srow = off >> 7;                // 0..31: row within chunk
  const int schunk = (off >> 4) & 7;        // 16B slot within row
  const int sxc = schunk ^ (srow & 7);      // swizzled source chunk
  const int scol = sxc * 8;                 // u16 col within BK=64

  const int rsw = lrow & 7;                 // read-side swizzle key

  for (int k0 = kbeg; k0 < kend; k0 += 64) {
    const u16* ga = A + (size_t)(m0 + srow) * K + k0 + scol;
    const u16* gb = BT + (size_t)(n0 + srow) * K + k0 + scol;
#pragma unroll
    for (int c = 0; c < 4; ++c) {
      GLDS16(ga + (size_t)(c * 32) * K, (char*)lsA + c * 4096 + off);
      GLDS16(gb + (size_t)(c * 32) * K, (char*)lsB + c * 4096 + off);
    }
    __syncthreads();
#pragma unroll
    for (int ks = 0; ks < 2; ++ks) {
      const int slot = ((ks * 4 + quad) ^ rsw) * 8;
      bf16x8 af[4], bfr[4];
#pragma unroll
      for (int ms = 0; ms < 4; ++ms)
        af[ms] = *(const bf16x8*)&lsA[(wm * 64 + ms * 16 + lrow) * 64 + slot];
#pragma unroll
      for (int ns = 0; ns < 4; ++ns)
        bfr[ns] = *(const bf16x8*)&lsB[(wn * 64 + ns * 16 + lrow) * 64 + slot];
#pragma unroll
      for (int ms = 0; ms < 4; ++ms)
#pragma unroll
        for (int ns = 0; ns < 4; ++ns)
          acc[ms][ns] = MFMA_BF16(af[ms], bfr[ns], acc[ms][ns]);
    }
    __syncthreads();
  }

  float* const pf = (EPI == 3) ? outf + (size_t)blockIdx.z * M * N : outf;
#pragma unroll
  for (int ms = 0; ms < 4; ++ms) {
    const int rbase = m0 + wm * 64 + ms * 16 + quad * 4;
#pragma unroll
    for (int ns = 0; ns < 4; ++ns) {
      const int col = n0 + wn * 64 + ns * 16 + lrow;
      if constexpr (EPI == 3) {
#pragma unroll
        for (int r = 0; r < 4; ++r)
          pf[(size_t)(rbase + r) * N + col] = acc[ms][ns][r];
      } else if constexpr (EPI == 2) {
        const float bcol = bias[col];
#pragma unroll
        for (int r = 0; r < 4; ++r) {
          float v = acc[ms][ns][r] + bcol;
          float g = 0.5f * v * (1.0f + erff(v * 0.7071067811865476f));
          outb[(size_t)(rbase + r) * N + col] = f2bf(g);
        }
      } else {  // QKV scatter
        const float bcol = bias[col];
        const int which = col / 768;
        const int rem = col - which * 768;
        const int hh = rem >> 6, dd = rem & 63;
        const int bI = rbase >> 11, sI = rbase & 2047;
        const size_t bh = (size_t)bI * 12 + hh;
        if (which == 0) {
#pragma unroll
          for (int r = 0; r < 4; ++r)
            qo[(bh * 2048 + sI + r) * 64 + dd] = f2bf((acc[ms][ns][r] + bcol) * QSCALE);
        } else if (which == 1) {
#pragma unroll
          for (int r = 0; r < 4; ++r)
            ko[(bh * 2048 + sI + r) * 64 + dd] = f2bf(acc[ms][ns][r] + bcol);
        } else {
          ushort4 pk;
          pk.x = f2bf(acc[ms][ns][0] + bcol);
          pk.y = f2bf(acc[ms][ns][1] + bcol);
          pk.z = f2bf(acc[ms][ns][2] + bcol);
          pk.w = f2bf(acc[ms][ns][3] + bcol);
          *(ushort4*)(vto + (bh * 64 + dd) * 2048 + sI) = pk;
        }
      }
    }
  }
}

// ---------------- flash attention (softmax-lite, XOR-swizzled LDS) ----------------
__global__ __launch_bounds__(256) void attn_kernel(
    const u16* __restrict__ q, const u16* __restrict__ k,
    const u16* __restrict__ vT, u16* __restrict__ ctx) {
  __shared__ __align__(16) u16 lsK[64 * 64];      // [s][d], swizzled
  __shared__ __align__(16) u16 lsV[64 * 64];      // [d][s], swizzled
  __shared__ __align__(16) u16 lsP[4][16 * 64];   // per-wave [m][j], swizzled
  const int tid = threadIdx.x;
  const int w = tid >> 6, lane = tid & 63;
  const int lrow = lane & 15, quad = lane >> 4;
  const int bh = blockIdx.y;
  const int b = bh / 12, h = bh - b * 12;
  const int q0 = blockIdx.x * 64;

  const u16* qbase = q + (size_t)bh * 2048 * 64;
  const u16* kbase = k + (size_t)bh * 2048 * 64;
  const u16* vbase = vT + (size_t)bh * 64 * 2048;

  const int qrow = q0 + w * 16 + lrow;
  const bf16x8 qf0 = *(const bf16x8*)(qbase + (size_t)qrow * 64 + quad * 8);
  const bf16x8 qf1 = *(const bf16x8*)(qbase + (size_t)qrow * 64 + 32 + quad * 8);

  float lsum[4] = {0.f, 0.f, 0.f, 0.f};
  f32x4 oacc[4];
#pragma unroll
  for (int d = 0; d < 4; ++d) oacc[d] = (f32x4){0.f, 0.f, 0.f, 0.f};

  const int off = tid * 16;
  const int srow = off >> 7;               // 0..31 (row within half-tile)
  const int schunk = (off >> 4) & 7;       // chunk slot within row
  const int sxc = schunk ^ (srow & 7);     // source chunk
  const int ksrc = srow * 64 + sxc * 8;    // u16 offset within K half-tile
  const int vsrc0 = srow * 2048 + sxc * 8; // u16 offset for V (row d=srow)

  const int c0 = quad ^ (lrow & 7);
  const int rd0 = c0 * 8, rd1 = (c0 ^ 4) * 8;  // u16 offsets within a row

  u16* const lsPw = &lsP[w][0];
  const int jhi_base = lrow >> 3, jlo = lrow & 7;

  for (int kt = 0; kt < 2048; kt += 64) {
    GLDS16(kbase + (size_t)kt * 64 + ksrc, (char*)lsK + off);
    GLDS16(kbase + (size_t)(kt + 32) * 64 + ksrc, (char*)lsK + 4096 + off);
    GLDS16(vbase + vsrc0 + kt, (char*)lsV + off);
    GLDS16(vbase + vsrc0 + kt + 32 * 2048, (char*)lsV + 4096 + off);
    __syncthreads();

    f32x4 sc[4];
#pragma unroll
    for (int ns = 0; ns < 4; ++ns) {
      sc[ns] = (f32x4){0.f, 0.f, 0.f, 0.f};
      const u16* kr = &lsK[(ns * 16 + lrow) * 64];
      bf16x8 kf0 = *(const bf16x8*)(kr + rd0);
      bf16x8 kf1 = *(const bf16x8*)(kr + rd1);
      sc[ns] = MFMA_BF16(qf0, kf0, sc[ns]);
      sc[ns] = MFMA_BF16(qf1, kf1, sc[ns]);
    }

#pragma unroll
    for (int ns = 0; ns < 4; ++ns) {
      const int jhi = ns * 2 + jhi_base;
#pragma unroll
      for (int r = 0; r < 4; ++r) {
        float p = __builtin_amdgcn_exp2f(sc[ns][r]);
        lsum[r] += p;
        union { float f; unsigned u; } cv; cv.f = p;
        const int m = quad * 4 + r;
        lsPw[m * 64 + ((jhi ^ (m & 7)) * 8) + jlo] = (u16)(cv.u >> 16);
      }
    }

    const u16* pr = lsPw + lrow * 64;
    const bf16x8 pf0 = *(const bf16x8*)(pr + rd0);
    const bf16x8 pf1 = *(const bf16x8*)(pr + rd1);
#pragma unroll
    for (int d = 0; d < 4; ++d) {
      const u16* vr = &lsV[(d * 16 + lrow) * 64];
      bf16x8 vf0 = *(const bf16x8*)(vr + rd0);
      bf16x8 vf1 = *(const bf16x8*)(vr + rd1);
      oacc[d] = MFMA_BF16(pf0, vf0, oacc[d]);
      oacc[d] = MFMA_BF16(pf1, vf1, oacc[d]);
    }
    __syncthreads();
  }

#pragma unroll
  for (int r = 0; r < 4; ++r) {
#pragma unroll
    for (int mm = 1; mm <= 8; mm <<= 1) lsum[r] += __shfl_xor(lsum[r], mm);
  }
  float invl[4];
#pragma unroll
  for (int r = 0; r < 4; ++r) invl[r] = 1.f / lsum[r];

  const int srow_out = q0 + w * 16 + quad * 4;
#pragma unroll
  for (int d = 0; d < 4; ++d)
#pragma unroll
    for (int r = 0; r < 4; ++r)
      ctx[(size_t)(b * 2048 + srow_out + r) * 768 + h * 64 + d * 16 + lrow] =
          f2bf(oacc[d][r] * invl[r]);
}

// ---------------- partial-sum + bias + residual + layernorm ----------------
// t = sum_{p<nparts} parts[p*PSTRIDE + row*768 + c] + bias[c] + res[row*768 + c]
__global__ __launch_bounds__(256) void ln_kernel(
    const float* __restrict__ parts, int nparts, const float* __restrict__ bias,
    const float* __restrict__ res, const float* __restrict__ g,
    const float* __restrict__ bb, float* __restrict__ outf, u16* __restrict__ outb) {
  const int row = blockIdx.x;
  const int tid = threadIdx.x;
  const float* pr = res + (size_t)row * 768;
  float v[3], s = 0.f, s2 = 0.f;
#pragma unroll
  for (int j = 0; j < 3; ++j) {
    const int c = tid + j * 256;
    float t = bias[c] + pr[c];
    for (int p = 0; p < nparts; ++p)
      t += parts[p * PSTRIDE + (size_t)row * 768 + c];
    v[j] = t; s += t; s2 += t * t;
  }
#pragma unroll
  for (int m = 32; m > 0; m >>= 1) {
    s += __shfl_xor(s, m);
    s2 += __shfl_xor(s2, m);
  }
  __shared__ float red[8];
  const int w = tid >> 6, lane = tid & 63;
  if (lane == 0) { red[w] = s; red[4 + w] = s2; }
  __syncthreads();
  s = red[0] + red[1] + red[2] + red[3];
  s2 = red[4] + red[5] + red[6] + red[7];
  const float mu = s * (1.f / 768.f);
  const float var = s2 * (1.f / 768.f) - mu * mu;
  const float rstd = rsqrtf(var + 1e-5f);
#pragma unroll
  for (int j = 0; j < 3; ++j) {
    const int c = tid + j * 256;
    const float y = (v[j] - mu) * rstd * g[c] + bb[c];
    if (outf) outf[(size_t)row * 768 + c] = y;
    if (outb) outb[(size_t)row * 768 + c] = f2bf(y);
  }
}

// ---------------- launch ----------------
extern "C" void kernel_launch(void* const* d_in, const int* in_sizes, int n_in,
                              void* d_out, int out_size, void* d_ws, size_t ws_size,
                              hipStream_t stream) {
  const float* x    = (const float*)d_in[0];
  const float* Wq   = (const float*)d_in[1];
  const float* bq   = (const float*)d_in[2];
  const float* Wk   = (const float*)d_in[3];
  const float* bk   = (const float*)d_in[4];
  const float* Wv   = (const float*)d_in[5];
  const float* bv   = (const float*)d_in[6];
  const float* Wo   = (const float*)d_in[7];
  const float* bo   = (const float*)d_in[8];
  const float* W1   = (const float*)d_in[9];
  const float* b1   = (const float*)d_in[10];
  const float* W2   = (const float*)d_in[11];
  const float* b2   = (const float*)d_in[12];
  const float* ln1g = (const float*)d_in[13];
  const float* ln1b = (const float*)d_in[14];
  const float* ln2g = (const float*)d_in[15];
  const float* ln2b = (const float*)d_in[16];

  char* ws = (char*)d_ws;
  size_t off = 0;
  auto alloc = [&](size_t bytes) {
    void* p = ws + off;
    off += (bytes + 255) & ~(size_t)255;
    return p;
  };
  // persistent weights
  u16*  WqkvT = (u16*)alloc(2304ull * 768 * 2);
  u16*  WoT   = (u16*)alloc(768ull * 768 * 2);
  u16*  W1T   = (u16*)alloc(3072ull * 768 * 2);
  u16*  W2T   = (u16*)alloc(768ull * 3072 * 2);
  float* bqkv = (float*)alloc(2304 * 4);
  // big aliased region: [xb qb kb vtb ctx attno(2 partials)] ; f2b(4 partials) overlays it
  char* bigbase = (char*)alloc(0);
  u16*  xb    = (u16*)alloc(4096ull * 768 * 2);
  u16*  qb    = (u16*)alloc(24ull * 2048 * 64 * 2);
  u16*  kb    = (u16*)alloc(24ull * 2048 * 64 * 2);
  u16*  vtb   = (u16*)alloc(24ull * 64 * 2048 * 2);
  u16*  ctx   = (u16*)alloc(4096ull * 768 * 2);
  float* attno = (float*)alloc(2ull * PSTRIDE * 4);   // Wo partials (z=2)
  float* f2b   = (float*)bigbase;                     // FFN2 partials (z=4), aliased
  // tail
  float* hbuf  = (float*)alloc(4096ull * 768 * 4);
  u16*  hb    = (u16*)alloc(4096ull * 768 * 2);
  u16*  f1    = (u16*)alloc(4096ull * 3072 * 2);

  transpose_bf16_k<<<dim3(24, 24), 256, 0, stream>>>(Wq, WqkvT, 768, 768);
  transpose_bf16_k<<<dim3(24, 24), 256, 0, stream>>>(Wk, WqkvT + 768 * 768, 768, 768);
  transpose_bf16_k<<<dim3(24, 24), 256, 0, stream>>>(Wv, WqkvT + 2 * 768 * 768, 768, 768);
  transpose_bf16_k<<<dim3(24, 24), 256, 0, stream>>>(Wo, WoT, 768, 768);
  transpose_bf16_k<<<dim3(96, 24), 256, 0, stream>>>(W1, W1T, 768, 3072);
  transpose_bf16_k<<<dim3(24, 96), 256, 0, stream>>>(W2, W2T, 3072, 768);
  concat3_k<<<9, 256, 0, stream>>>(bq, bk, bv, bqkv);
  cvt_bf16_k<<<3072, 256, 0, stream>>>(x, xb, 4096 * 768);

  // QKV: M=4096 N=2304 K=768
  gemm_bt<0><<<dim3(18, 32, 1), 256, 0, stream>>>(xb, WqkvT, bqkv, 4096, 2304, 768, 768,
                                                  nullptr, nullptr, qb, kb, vtb);
  attn_kernel<<<dim3(32, 24), 256, 0, stream>>>(qb, kb, vtb, ctx);
  // Wo: split-K z=2 -> 2 fp32 partials in attno
  gemm_bt<3><<<dim3(6, 32, 2), 256, 0, stream>>>(ctx, WoT, nullptr, 4096, 768, 768, 384,
                                                 attno, nullptr, nullptr, nullptr, nullptr);
  ln_kernel<<<4096, 256, 0, stream>>>(attno, 2, bo, x, ln1g, ln1b, hbuf, hb);
  // FFN1: M=4096 N=3072 K=768, GELU epilogue
  gemm_bt<2><<<dim3(24, 32, 1), 256, 0, stream>>>(hb, W1T, b1, 4096, 3072, 768, 768,
                                                  nullptr, f1, nullptr, nullptr, nullptr);
  // FFN2: split-K z=4 -> 4 fp32 partials in f2b (aliased over dead buffers)
  gemm_bt<3><<<dim3(6, 32, 4), 256, 0, stream>>>(f1, W2T, nullptr, 4096, 768, 3072, 768,
                                                 f2b, nullptr, nullptr, nullptr, nullptr);
  ln_kernel<<<4096, 256, 0, stream>>>(f2b, 4, b2, hbuf, ln2g, ln2b, (float*)d_out, nullptr);
}